// Round 16
// baseline (1667.981 us; speedup 1.0000x reference)
//
#include <hip/hip_runtime.h>
#include <cstdio>

#define NODES 153600
#define PJ 150
#define NJETS 1024
#define DEG 16
#define NEDGE (NODES*DEG)
#define HD 256
#define NCL 10

#define LSTR 192   // Ls/Tt row stride (u16): conflicts killed by seg XOR-swizzle (key = lr&7)
#define TNS  64    // Tn row stride (u16): seg XOR-swizzle (key = lr&7)
#define OSTR 264   // OutS staging row stride (u16)

typedef unsigned short u16;  // fp16 bit pattern
typedef _Float16 f16;
typedef f16 f16x8 __attribute__((ext_vector_type(8)));
typedef u16 u16x8 __attribute__((ext_vector_type(8)));
typedef u16 u16x4 __attribute__((ext_vector_type(4)));
typedef float f32x4 __attribute__((ext_vector_type(4)));

__device__ inline float h2f(u16 u) { union { u16 s; f16 h; } v; v.s = u; return (float)v.h; }
__device__ inline u16 f2h(float f) { union { u16 s; f16 h; } v; v.h = (f16)f; return v.s; }
// XOR-swizzle a 16B segment index within its aligned 8-seg (128B) block
__device__ inline int swz(int seg, int key) { return (seg & ~7) | ((seg & 7) ^ (key & 7)); }

// ---------------- diagnostic ----------------
__global__ void k_diag(float* out, float code) {
  if (blockIdx.x == 0 && threadIdx.x == 0) out[0] = code;
}

// ---------------- graph preprocessing ----------------

__global__ __launch_bounds__(256) void k_discounts(const int* __restrict__ tgt,
                                                   int* __restrict__ counts,
                                                   float* __restrict__ dis) {
  int i = blockIdx.x*256 + threadIdx.x;
  if (i < NEDGE) atomicAdd(&counts[tgt[i]], 1);
  if (i < NODES) {
    int cnt = 0;
#pragma unroll
    for (int j = 0; j < DEG; ++j) cnt += (tgt[i*DEG + j] != i) ? 1 : 0;
    dis[i] = (cnt > 0) ? rsqrtf((float)cnt) : 0.f;
  }
}

__global__ __launch_bounds__(256) void k_scan(const int* __restrict__ counts, int* __restrict__ rowptr, int* __restrict__ cursor) {
  int j = blockIdx.x*256 + threadIdx.x;
  if (j >= NJETS) return;
  int run = j*PJ*DEG;
  for (int l = 0; l < PJ; ++l) {
    int idx = j*PJ + l;
    int cnt = counts[idx];
    rowptr[idx] = run;
    cursor[idx] = run;
    run += cnt;
  }
  if (j == 0) rowptr[NODES] = NEDGE;
}

__global__ __launch_bounds__(256) void k_fill(const int* __restrict__ src_, const int* __restrict__ tgt_,
                                              const float* __restrict__ dis, int* __restrict__ cursor,
                                              unsigned char* __restrict__ ccol, float* __restrict__ cw) {
  int e = blockIdx.x*256 + threadIdx.x;
  if (e >= NEDGE) return;
  int s = src_[e], t = tgt_[e];
  int pos = atomicAdd(&cursor[t], 1);
  ccol[pos] = (unsigned char)(s % PJ);
  cw[pos] = (s != t) ? -(dis[s]*dis[t]) : 0.f;
}

// ---------------- W conversion + stats/rn zeroing ----------------
__global__ __launch_bounds__(256) void k_prepW(const float* __restrict__ Wa, const float* __restrict__ Wb,
                                               const float* __restrict__ Wc, u16* __restrict__ WT,
                                               float* __restrict__ stats /*[3][512]*/,
                                               float* __restrict__ rn) {
  int i = blockIdx.x*256 + threadIdx.x;
  if (i < 3*256*1536) {
    int layer = i / (256*1536);
    int rem = i - layer*(256*1536);
    int cout = rem / 1536, k = rem - cout*1536;
    int term = k >> 8, cin = k & 255;
    const float* W = (layer == 0) ? Wa : (layer == 1) ? Wb : Wc;
    WT[i] = f2h(W[(size_t)term*65536 + cin*256 + cout]);
  }
  if (i < 3*2*HD) stats[i] = 0.f;
  if (i < NODES) rn[i] = 0.f;
}

// ---------------- layer 1 fused: 5 sparse props (din=3) + [150x18]@[18x256] + BN stats ------------
__global__ __launch_bounds__(512) void k_l1(const float* __restrict__ x,
                                            const int* __restrict__ rowptr,
                                            const unsigned char* __restrict__ ccol,
                                            const float* __restrict__ cw,
                                            const float* __restrict__ W1,
                                            const float* __restrict__ b1,
                                            float* __restrict__ stats,
                                            u16* __restrict__ outc) {
  __shared__ float Ta[450], Tb[450];
  __shared__ float Tall_s[PJ*18];
  __shared__ float wl[18*256];
  __shared__ float cw_s[PJ*DEG];
  __shared__ u16  col_s[PJ*DEG];
  __shared__ int  rp_s[PJ+1];
  int j = blockIdx.x, tid = threadIdx.x;
  int jb = j*PJ, e0 = jb*DEG;
  for (int i = tid; i < 18*256; i += 512) wl[i] = W1[i];
  for (int i = tid; i < PJ*DEG; i += 512) { cw_s[i] = cw[e0+i]; col_s[i] = (u16)ccol[e0+i]; }
  for (int i = tid; i < PJ+1; i += 512) rp_s[i] = rowptr[jb+i] - e0;
  if (tid < 450) Ta[tid] = x[(size_t)jb*3 + tid];
  __syncthreads();
  int r = tid/3, c = tid - r*3;
  float* cur = Ta; float* oth = Tb;
  if (tid < 450) Tall_s[r*18 + c] = cur[tid];
  for (int t = 1; t < 6; ++t) {
    if (tid < 450) {
      int es = rp_s[r], ee = rp_s[r+1];
      float acc = 0.f;
      for (int e = es; e < ee; ++e) acc += cw_s[e]*cur[(int)col_s[e]*3 + c];
      float v = (t == 1) ? acc : 2.f*acc - oth[tid];
      oth[tid] = v;
      Tall_s[r*18 + t*3 + c] = v;
    }
    __syncthreads();
    float* tmp = cur; cur = oth; oth = tmp;
  }
  int cc = tid & 255, rhalf = tid >> 8;
  float bc = b1[cc];
  float s = 0.f, s2 = 0.f;
  int r0 = rhalf*75;
  for (int rr = r0; rr < r0 + 75; ++rr) {
    float acc = 0.f;
#pragma unroll
    for (int i = 0; i < 18; ++i) acc += Tall_s[rr*18 + i] * wl[i*256 + cc];
    outc[(size_t)(jb+rr)*HD + cc] = f2h(acc);
    float vb = acc + bc;
    s += vb; s2 += vb*vb;
  }
  atomicAdd(&stats[cc], s);
  atomicAdd(&stats[HD + cc], s2);
}

// ---------------- fused per-jet Chebyshev layer ----------------
// r15 structure + (a) term-level WT load batching (8 named f16x8 issued before the
// term's MFMAs), (b) coalesced OUT writes via LDS re-staging after the final barrier.
template<int OMODE>
__global__ __launch_bounds__(1024, 4) void k_cheb(const u16* __restrict__ IN,
                                                  const u16* __restrict__ WTu,
                                                  const int* __restrict__ rowptr,
                                                  const unsigned char* __restrict__ ccol,
                                                  const float* __restrict__ cw,
                                                  const float* __restrict__ statsPrev,
                                                  const float* __restrict__ gP,
                                                  const float* __restrict__ beP,
                                                  const float* __restrict__ bP,
                                                  const float* __restrict__ bCur,
                                                  float* __restrict__ statsCur,
                                                  float* __restrict__ rn,
                                                  u16* __restrict__ OUTp) {
  __shared__ u16 SM[75776];            // Ls | Tn0 | Tn1 | Tt0 | Tt1  (151.5 KB)
  __shared__ float bnA[HD], bnB[HD];   // 2 KB
  u16* Ls  = SM;                       // 160*192 = 30720
  u16* Tn0 = SM + 30720;               // 160*64  = 10240
  u16* Tn1 = SM + 40960;
  u16* Tt0 = SM + 51200;               // 64*192  = 12288
  u16* Tt1 = SM + 63488;
  int j = blockIdx.x, tid = threadIdx.x;
  int jb = j*PJ;
  int lane = tid & 63, wid = tid >> 6;
  int wm = wid >> 3, wn = wid & 7;          // 2(M) x 8(N)
  int lr = lane & 15, lg = lane >> 4;
  int ph = wn >> 2, cs = wn & 3;            // prop: half + 16-ch slice
  int cown = cs*16 + lr;
  u16* Tnp = ph ? Tn1 : Tn0;
  u16* Ttp = ph ? Tt1 : Tt0;
  // hoisted thread-invariant swizzle offsets (u16 units)
  int key   = lr & 7;
  int segA0 = ((lg    ) ^ key) * 8;
  int segA1 = ((lg + 4) ^ key) * 8;
  int pOff[5] = { segA0, segA1, 64 + segA0, 64 + segA1, 128 + segA0 };
  int ep0 = ((cown >> 3) ^ ((lg & 1)*4 + 0)) * 8 + (cown & 7);
  int ep1 = ((cown >> 3) ^ ((lg & 1)*4 + 1)) * 8 + (cown & 7);
  int ep2 = ((cown >> 3) ^ ((lg & 1)*4 + 2)) * 8 + (cown & 7);
  int ep3 = ((cown >> 3) ^ ((lg & 1)*4 + 3)) * 8 + (cown & 7);
  int cownL = cown * LSTR;
  const f16* WT = (const f16*)WTu;
  const f16* wtb = WT + (size_t)(wn*32 + lr)*1536 + lg*8;

  // BN tables
  if (tid < HD) {
    const float invN = 1.f/(float)NODES;
    float m = statsPrev[tid]*invN;
    float var = statsPrev[HD+tid]*invN - m*m;
    float A = rsqrtf(var + 1e-5f) * gP[tid];
    bnA[tid] = A;
    bnB[tid] = (bP[tid] - m)*A + beP[tid];
  }
  // zero Ls + Tn pad rows (150..159, both halves)
  {
    u16x8 z = {0,0,0,0,0,0,0,0};
    for (int i = tid; i < 3840; i += 1024) *(u16x8*)&Ls[i*8] = z;
    for (int i = tid; i < 160; i += 1024) {
      int h = i >= 80 ? 1 : 0;
      int rem = i - h*80;
      int row = 150 + (rem >> 3), seg = rem & 7;
      u16* TnH = h ? Tn1 : Tn0;
      *(u16x8*)&TnH[row*TNS + seg*8] = z;
    }
  }
  __syncthreads();
  // build dense 2*Lhat in LDS from CSR (thread r owns row r)
  if (tid < PJ) {
    int es = rowptr[jb + tid], ee = rowptr[jb + tid + 1];
    for (int e = es; e < ee; ++e) {
      int c = (int)ccol[e];
      int a = tid*LSTR + swz(c >> 3, tid)*8 + (c & 7);
      Ls[a] = f2h(h2f(Ls[a]) + 2.f*cw[e]);
    }
  }
  f32x4 acc[5][2];
#pragma unroll
  for (int a = 0; a < 5; ++a)
#pragma unroll
    for (int b = 0; b < 2; ++b) acc[a][b] = (f32x4)0.f;

  u16x4 tc0, tc1, tc2, tc3, tc4, tp0, tp1, tp2, tp3, tp4;

  for (int qp = 0; qp < 2; ++qp) {
    __syncthreads();   // prior-pair reads done; Ls build / bn staged at qp=0
    // stage T0 = lrelu(BN(IN)) for quarters (qp*2, qp*2+1); rows < 150 only
    for (int i = tid; i < 2400; i += 1024) {
      int h = (i >= 1200) ? 1 : 0;
      int rem = i - h*1200;
      int row = rem >> 3, seg = rem & 7;
      int c0 = (qp*2+h)*64 + seg*8;
      u16x8 v = *(const u16x8*)&IN[(size_t)(jb+row)*HD + c0];
      u16x8 o;
#pragma unroll
      for (int u = 0; u < 8; ++u) {
        float f = h2f(v[u])*bnA[c0+u] + bnB[c0+u];
        o[u] = f2h((f > 0.f) ? f : 0.01f*f);
      }
      u16* TnH = h ? Tn1 : Tn0;
      *(u16x8*)&TnH[row*TNS + (seg ^ (row & 7))*8] = o;
    }
    __syncthreads();
    // build Ttr (swizzled both sides)
    for (int i = tid; i < 2560; i += 1024) {
      int h = (i >= 1280) ? 1 : 0;
      int rem = i - h*1280;
      int c = rem & 63, m = rem >> 6;
      u16* TnH = h ? Tn1 : Tn0;
      u16* TtH = h ? Tt1 : Tt0;
      u16x8 v;
#pragma unroll
      for (int u = 0; u < 8; ++u) {
        int r = m*8 + u;
        v[u] = TnH[r*TNS + ((c >> 3) ^ (r & 7))*8 + (c & 7)];
      }
      *(u16x8*)&TtH[c*LSTR + swz(m, c)*8] = v;
    }
    // own-slot T0 into named registers
#define TINIT(MF, TC, TP) { int r0 = wm*80 + MF*16 + lg*4; u16x4 t; \
    t[0] = Tnp[(r0+0)*TNS + ep0]; t[1] = Tnp[(r0+1)*TNS + ep1]; \
    t[2] = Tnp[(r0+2)*TNS + ep2]; t[3] = Tnp[(r0+3)*TNS + ep3]; \
    TC = t; TP = t; }
    TINIT(0, tc0, tp0) TINIT(1, tc1, tp1) TINIT(2, tc2, tp2) TINIT(3, tc3, tp3) TINIT(4, tc4, tp4)
#undef TINIT
    __syncthreads();
#pragma unroll 1
    for (int t = 0; t < 6; ++t) {
      // ---- batched WT loads for the whole term (8 x f16x8, named) ----
      int kb0 = t*256 + qp*128;
      f16x8 w000 = *(const f16x8*)&wtb[        kb0      ];
      f16x8 w001 = *(const f16x8*)&wtb[24576 + kb0      ];
      f16x8 w010 = *(const f16x8*)&wtb[        kb0 + 32 ];
      f16x8 w011 = *(const f16x8*)&wtb[24576 + kb0 + 32 ];
      f16x8 w100 = *(const f16x8*)&wtb[        kb0 + 64 ];
      f16x8 w101 = *(const f16x8*)&wtb[24576 + kb0 + 64 ];
      f16x8 w110 = *(const f16x8*)&wtb[        kb0 + 96 ];
      f16x8 w111 = *(const f16x8*)&wtb[24576 + kb0 + 96 ];
      // ---- weight GEMM: acc += T_t @ W_t (wave tile 80x32, both halves) ----
#define WGEMM(TNH, SEGA, BV0, BV1) { f16x8 a_[5]; \
      _Pragma("unroll") for (int mf = 0; mf < 5; ++mf) { \
        int row = wm*80 + mf*16 + lr; \
        a_[mf] = *(const f16x8*)&TNH[row*TNS + SEGA]; } \
      _Pragma("unroll") for (int mf = 0; mf < 5; ++mf) { \
        acc[mf][0] = __builtin_amdgcn_mfma_f32_16x16x32_f16(a_[mf], BV0, acc[mf][0], 0, 0, 0); \
        acc[mf][1] = __builtin_amdgcn_mfma_f32_16x16x32_f16(a_[mf], BV1, acc[mf][1], 0, 0, 0); } }
      WGEMM(Tn0, segA0, w000, w001)
      WGEMM(Tn0, segA1, w010, w011)
      WGEMM(Tn1, segA0, w100, w101)
      WGEMM(Tn1, segA1, w110, w111)
#undef WGEMM
      if (t < 5) {
        // ---- prop MFMA: pacc = L2 @ T_t for this wave's (half, 16-ch slice) ----
        f32x4 pacc[5];
#pragma unroll
        for (int mf = 0; mf < 5; ++mf) pacc[mf] = (f32x4)0.f;
#pragma unroll
        for (int ks = 0; ks < 5; ++ks) {
          f16x8 b = *(const f16x8*)&Ttp[cownL + pOff[ks]];
#pragma unroll
          for (int mf = 0; mf < 5; ++mf) {
            int row = wm*80 + mf*16 + lr;
            f16x8 a = *(const f16x8*)&Ls[row*LSTR + pOff[ks]];
            pacc[mf] = __builtin_amdgcn_mfma_f32_16x16x32_f16(a, b, pacc[mf], 0, 0, 0);
          }
        }
        __syncthreads();
#define TEPI(MF, TC, TP) { int r0 = wm*80 + MF*16 + lg*4; u16x4 o; \
        { float v0_ = (t == 0) ? 0.5f*pacc[MF][0] : pacc[MF][0] - h2f(TP[0]); o[0] = f2h(v0_); } \
        { float v1_ = (t == 0) ? 0.5f*pacc[MF][1] : pacc[MF][1] - h2f(TP[1]); o[1] = f2h(v1_); } \
        { float v2_ = (t == 0) ? 0.5f*pacc[MF][2] : pacc[MF][2] - h2f(TP[2]); o[2] = f2h(v2_); } \
        { float v3_ = (t == 0) ? 0.5f*pacc[MF][3] : pacc[MF][3] - h2f(TP[3]); o[3] = f2h(v3_); } \
        Tnp[(r0+0)*TNS + ep0] = o[0]; Tnp[(r0+1)*TNS + ep1] = o[1]; \
        Tnp[(r0+2)*TNS + ep2] = o[2]; Tnp[(r0+3)*TNS + ep3] = o[3]; \
        int sgT = wm*10 + MF*2 + (lg >> 1); \
        int segT = (sgT & ~7) | ((sgT & 7) ^ key); \
        *(u16x4*)&Ttp[cownL + segT*8 + (lg & 1)*4] = o; \
        TP = TC; TC = o; }
        TEPI(0, tc0, tp0) TEPI(1, tc1, tp1) TEPI(2, tc2, tp2) TEPI(3, tc3, tp3) TEPI(4, tc4, tp4)
#undef TEPI
        __syncthreads();
      }
    }
  }
  // ---- epilogue: stats/rowsumsq from regs, then coalesced OUT via LDS re-staging ----
  __syncthreads();   // all waves done reading SM
  u16* OutS = SM;    // [150][OSTR] u16 = 79.2 KB, aliases Ls/Tn
  if (OMODE == 0) {
#pragma unroll
    for (int nf = 0; nf < 2; ++nf) {
      int col = wn*32 + nf*16 + lr;
      float bc = bCur[col];
      float s = 0.f, s2 = 0.f;
#pragma unroll
      for (int mf = 0; mf < 5; ++mf) {
        int row = wm*80 + mf*16 + lg*4;
#pragma unroll
        for (int e = 0; e < 4; ++e) {
          int r = row + e;
          if (r < PJ) {
            float v = acc[mf][nf][e];
            OutS[r*OSTR + col] = f2h(v);
            float vb = v + bc;
            s += vb; s2 += vb*vb;
          }
        }
      }
      s  += __shfl_xor(s, 16, 64);  s  += __shfl_xor(s, 32, 64);
      s2 += __shfl_xor(s2, 16, 64); s2 += __shfl_xor(s2, 32, 64);
      if (lg == 0) {
        atomicAdd(&statsCur[col], s);
        atomicAdd(&statsCur[HD + col], s2);
      }
    }
  } else {
    float bc[2];
#pragma unroll
    for (int nf = 0; nf < 2; ++nf) bc[nf] = bCur[wn*32 + nf*16 + lr];
#pragma unroll
    for (int mf = 0; mf < 5; ++mf) {
      int row = wm*80 + mf*16 + lg*4;
#pragma unroll
      for (int e = 0; e < 4; ++e) {
        int r = row + e;
        float srow = 0.f;
        if (r < PJ) {
#pragma unroll
          for (int nf = 0; nf < 2; ++nf) {
            int col = wn*32 + nf*16 + lr;
            float v = acc[mf][nf][e];
            OutS[r*OSTR + col] = f2h(v);
            float vb = v + bc[nf];
            srow += vb*vb;
          }
        }
        srow += __shfl_xor(srow, 1, 64);
        srow += __shfl_xor(srow, 2, 64);
        srow += __shfl_xor(srow, 4, 64);
        srow += __shfl_xor(srow, 8, 64);
        if (lr == 0 && r < PJ) atomicAdd(&rn[jb + r], srow);
      }
    }
  }
  __syncthreads();
  // coalesced write: 150 rows x 512B
  for (int i = tid; i < 4800; i += 1024) {
    int row = i >> 5, seg = i & 31;
    *(u16x8*)&OUTp[(size_t)(jb+row)*HD + seg*8] = *(const u16x8*)&OutS[row*OSTR + seg*8];
  }
}

// ---------------- distance softmax pooling, fused row-normalize ----------------

__global__ __launch_bounds__(256) void k_pool(const u16* __restrict__ h, const float* __restrict__ rn,
                                              const float* __restrict__ bias, const float* __restrict__ x,
                                              const float* __restrict__ centers, const float* __restrict__ log_temp,
                                              float* __restrict__ out) {
  __shared__ float a_s[PJ][NCL];
  __shared__ float colsum[NCL];
  __shared__ float inv_s[PJ];
  int j = blockIdx.x;
  int tid = threadIdx.x;
  float T = expf(fminf(fmaxf(log_temp[0], -2.f), 3.f));
  if (tid < PJ) {
    int g = j*PJ + tid;
    inv_s[tid] = 1.f / fmaxf(sqrtf(rn[g]), 1e-12f);
    float eta = x[(size_t)g*3], phi = x[(size_t)g*3 + 1];
    float d[NCL];
    float dmin = 1e30f;
#pragma unroll
    for (int k = 0; k < NCL; ++k) {
      float dx = eta - centers[2*k], dy = phi - centers[2*k+1];
      d[k] = dx*dx + dy*dy;
      dmin = fminf(dmin, d[k]);
    }
    float s = 0.f, ek[NCL];
#pragma unroll
    for (int k = 0; k < NCL; ++k) { ek[k] = expf(-T*(d[k]-dmin)); s += ek[k]; }
    float invs = 1.f/s;
#pragma unroll
    for (int k = 0; k < NCL; ++k) a_s[tid][k] = ek[k]*invs;
  }
  __syncthreads();
  if (tid < NCL) {
    float s = 0.f;
    for (int n = 0; n < PJ; ++n) s += a_s[n][tid];
    colsum[tid] = s;
  }
  __syncthreads();
  int c = tid;
  float bc = bias[c];
  float acc[NCL] = {};
  for (int n = 0; n < PJ; ++n) {
    float hv = (h2f(h[(size_t)(j*PJ + n)*HD + c]) + bc) * inv_s[n];
#pragma unroll
    for (int k = 0; k < NCL; ++k) acc[k] += a_s[n][k]*hv;
  }
#pragma unroll
  for (int k = 0; k < NCL; ++k)
    out[(size_t)j*(NCL*HD) + k*HD + c] = acc[k] / (colsum[k] + 1e-8f);
}

// ---------------- host ----------------

extern "C" void kernel_launch(void* const* d_in, const int* in_sizes, int n_in,
                              void* d_out, int out_size, void* d_ws, size_t ws_size,
                              hipStream_t stream) {
  (void)in_sizes; (void)n_in; (void)out_size;
  const float* x   = (const float*)d_in[0];
  const int*   ei  = (const int*)d_in[1];
  const int*   srcA = ei;
  const int*   tgtA = ei + NEDGE;
  const float* W1  = (const float*)d_in[3];
  const float* b1  = (const float*)d_in[4];
  const float* W2  = (const float*)d_in[5];
  const float* b2  = (const float*)d_in[6];
  const float* W3  = (const float*)d_in[7];
  const float* b3  = (const float*)d_in[8];
  const float* W4  = (const float*)d_in[9];
  const float* b4  = (const float*)d_in[10];
  const float* g1  = (const float*)d_in[11];
  const float* be1 = (const float*)d_in[12];
  const float* g2  = (const float*)d_in[13];
  const float* be2 = (const float*)d_in[14];
  const float* g3  = (const float*)d_in[15];
  const float* be3 = (const float*)d_in[16];
  const float* centers  = (const float*)d_in[17];
  const float* log_temp = (const float*)d_in[18];
  float* out = (float*)d_out;

  auto rb = [](size_t b) { return (b + 255) & ~(size_t)255; };
  size_t need = 2*rb((size_t)NODES*HD*2)            // OUTA, OUTB
              + rb((size_t)3*256*1536*2)            // Wcat
              + 3*rb((size_t)NODES*4)               // dis, counts, cursor
              + rb((size_t)(NODES+1)*4)             // rowptr
              + rb((size_t)NEDGE)                   // ccol
              + rb((size_t)NEDGE*4)                 // cw
              + rb((size_t)3*2*HD*4)                // stats x3
              + rb((size_t)NODES*4);                // rn
  fprintf(stderr, "[kernel_launch] ws_size=%zu need=%zu\n", ws_size, need);
  if (d_ws == nullptr || ws_size < need) {
    float code = 1.0e6f + (float)(ws_size >> 20);
    k_diag<<<1, 1, 0, stream>>>(out, code);
    return;
  }

  char* wp = (char*)d_ws;
  auto alloc = [&](size_t b) -> void* {
    void* p = (void*)wp;
    wp += (b + 255) & ~(size_t)255;
    return p;
  };
  u16*   OUTA = (u16*)alloc((size_t)NODES*HD*2);
  u16*   OUTB = (u16*)alloc((size_t)NODES*HD*2);
  u16*   Wcat = (u16*)alloc((size_t)3*256*1536*2);
  float* dis  = (float*)alloc((size_t)NODES*4);
  int*   counts = (int*)alloc((size_t)NODES*4);
  int*   cursor = (int*)alloc((size_t)NODES*4);
  int*   rowptr = (int*)alloc((size_t)(NODES+1)*4);
  unsigned char* ccol = (unsigned char*)alloc((size_t)NEDGE);
  float* cw     = (float*)alloc((size_t)NEDGE*4);
  float* stats  = (float*)alloc((size_t)3*2*HD*4);   // [3][512]
  float* rn     = (float*)alloc((size_t)NODES*4);
  float* s0 = stats, *s1 = stats + 512, *s2 = stats + 1024;

  // graph preprocessing
  hipMemsetAsync(counts, 0, (size_t)NODES*4, stream);
  k_discounts<<<(NEDGE+255)/256, 256, 0, stream>>>(tgtA, counts, dis);
  k_scan<<<(NJETS+255)/256, 256, 0, stream>>>(counts, rowptr, cursor);
  k_fill<<<(NEDGE+255)/256, 256, 0, stream>>>(srcA, tgtA, dis, cursor, ccol, cw);

  // W conversion + all stats/rn zeroing (independent of layer 1)
  k_prepW<<<(3*256*1536+255)/256, 256, 0, stream>>>(W2, W3, W4, Wcat, stats, rn);

  // ---- layer 1 fused (props + GEMM + stats) ----
  k_l1<<<NJETS, 512, 0, stream>>>(x, rowptr, ccol, cw, W1, b1, s0, OUTA);

  // ---- layers 2..4: fused all-MFMA Cheb, BN-on-stage, in-block L build ----
  k_cheb<0><<<NJETS, 1024, 0, stream>>>(OUTA, Wcat,            rowptr, ccol, cw, s0, g1, be1, b1, b2, s1, rn, OUTB);
  k_cheb<0><<<NJETS, 1024, 0, stream>>>(OUTB, Wcat + 393216,   rowptr, ccol, cw, s1, g2, be2, b2, b3, s2, rn, OUTA);
  k_cheb<1><<<NJETS, 1024, 0, stream>>>(OUTA, Wcat + 2*393216, rowptr, ccol, cw, s2, g3, be3, b3, b4, s2, rn, OUTB);

  // ---- pooling (fused rownorm) ----
  k_pool<<<NJETS, 256, 0, stream>>>(OUTB, rn, b4, x, centers, log_temp, out);
}

// Round 17
// 1378.727 us; speedup vs baseline: 1.2098x; 1.2098x over previous
//
#include <hip/hip_runtime.h>
#include <cstdio>

#define NODES 153600
#define PJ 150
#define NJETS 1024
#define DEG 16
#define NEDGE (NODES*DEG)
#define HD 256
#define NCL 10

#define LSTR 192   // Ls/Tt row stride (u16): conflicts killed by seg XOR-swizzle (key = lr&7)
#define TNS  64    // Tn row stride (u16): seg XOR-swizzle (key = lr&7)
#define OSTR 264   // OutS staging row stride (u16)

typedef unsigned short u16;  // fp16 bit pattern
typedef _Float16 f16;
typedef f16 f16x8 __attribute__((ext_vector_type(8)));
typedef u16 u16x8 __attribute__((ext_vector_type(8)));
typedef u16 u16x4 __attribute__((ext_vector_type(4)));
typedef float f32x4 __attribute__((ext_vector_type(4)));

__device__ inline float h2f(u16 u) { union { u16 s; f16 h; } v; v.s = u; return (float)v.h; }
__device__ inline u16 f2h(float f) { union { u16 s; f16 h; } v; v.h = (f16)f; return v.s; }
// XOR-swizzle a 16B segment index within its aligned 8-seg (128B) block
__device__ inline int swz(int seg, int key) { return (seg & ~7) | ((seg & 7) ^ (key & 7)); }

// ---------------- diagnostic ----------------
__global__ void k_diag(float* out, float code) {
  if (blockIdx.x == 0 && threadIdx.x == 0) out[0] = code;
}

// ---------------- graph preprocessing ----------------

__global__ __launch_bounds__(256) void k_discounts(const int* __restrict__ tgt,
                                                   int* __restrict__ counts,
                                                   float* __restrict__ dis) {
  int i = blockIdx.x*256 + threadIdx.x;
  if (i < NEDGE) atomicAdd(&counts[tgt[i]], 1);
  if (i < NODES) {
    int cnt = 0;
#pragma unroll
    for (int j = 0; j < DEG; ++j) cnt += (tgt[i*DEG + j] != i) ? 1 : 0;
    dis[i] = (cnt > 0) ? rsqrtf((float)cnt) : 0.f;
  }
}

__global__ __launch_bounds__(256) void k_scan(const int* __restrict__ counts, int* __restrict__ rowptr, int* __restrict__ cursor) {
  int j = blockIdx.x*256 + threadIdx.x;
  if (j >= NJETS) return;
  int run = j*PJ*DEG;
  for (int l = 0; l < PJ; ++l) {
    int idx = j*PJ + l;
    int cnt = counts[idx];
    rowptr[idx] = run;
    cursor[idx] = run;
    run += cnt;
  }
  if (j == 0) rowptr[NODES] = NEDGE;
}

__global__ __launch_bounds__(256) void k_fill(const int* __restrict__ src_, const int* __restrict__ tgt_,
                                              const float* __restrict__ dis, int* __restrict__ cursor,
                                              unsigned char* __restrict__ ccol, float* __restrict__ cw) {
  int e = blockIdx.x*256 + threadIdx.x;
  if (e >= NEDGE) return;
  int s = src_[e], t = tgt_[e];
  int pos = atomicAdd(&cursor[t], 1);
  ccol[pos] = (unsigned char)(s % PJ);
  cw[pos] = (s != t) ? -(dis[s]*dis[t]) : 0.f;
}

// ---------------- W conversion + stats/rn zeroing ----------------
__global__ __launch_bounds__(256) void k_prepW(const float* __restrict__ Wa, const float* __restrict__ Wb,
                                               const float* __restrict__ Wc, u16* __restrict__ WT,
                                               float* __restrict__ stats /*[3][512]*/,
                                               float* __restrict__ rn) {
  int i = blockIdx.x*256 + threadIdx.x;
  if (i < 3*256*1536) {
    int layer = i / (256*1536);
    int rem = i - layer*(256*1536);
    int cout = rem / 1536, k = rem - cout*1536;
    int term = k >> 8, cin = k & 255;
    const float* W = (layer == 0) ? Wa : (layer == 1) ? Wb : Wc;
    WT[i] = f2h(W[(size_t)term*65536 + cin*256 + cout]);
  }
  if (i < 3*2*HD) stats[i] = 0.f;
  if (i < NODES) rn[i] = 0.f;
}

// ---------------- layer 1 fused: 5 sparse props (din=3) + [150x18]@[18x256] + BN stats ------------
__global__ __launch_bounds__(512) void k_l1(const float* __restrict__ x,
                                            const int* __restrict__ rowptr,
                                            const unsigned char* __restrict__ ccol,
                                            const float* __restrict__ cw,
                                            const float* __restrict__ W1,
                                            const float* __restrict__ b1,
                                            float* __restrict__ stats,
                                            u16* __restrict__ outc) {
  __shared__ float Ta[450], Tb[450];
  __shared__ float Tall_s[PJ*18];
  __shared__ float wl[18*256];
  __shared__ float cw_s[PJ*DEG];
  __shared__ u16  col_s[PJ*DEG];
  __shared__ int  rp_s[PJ+1];
  int j = blockIdx.x, tid = threadIdx.x;
  int jb = j*PJ, e0 = jb*DEG;
  for (int i = tid; i < 18*256; i += 512) wl[i] = W1[i];
  for (int i = tid; i < PJ*DEG; i += 512) { cw_s[i] = cw[e0+i]; col_s[i] = (u16)ccol[e0+i]; }
  for (int i = tid; i < PJ+1; i += 512) rp_s[i] = rowptr[jb+i] - e0;
  if (tid < 450) Ta[tid] = x[(size_t)jb*3 + tid];
  __syncthreads();
  int r = tid/3, c = tid - r*3;
  float* cur = Ta; float* oth = Tb;
  if (tid < 450) Tall_s[r*18 + c] = cur[tid];
  for (int t = 1; t < 6; ++t) {
    if (tid < 450) {
      int es = rp_s[r], ee = rp_s[r+1];
      float acc = 0.f;
      for (int e = es; e < ee; ++e) acc += cw_s[e]*cur[(int)col_s[e]*3 + c];
      float v = (t == 1) ? acc : 2.f*acc - oth[tid];
      oth[tid] = v;
      Tall_s[r*18 + t*3 + c] = v;
    }
    __syncthreads();
    float* tmp = cur; cur = oth; oth = tmp;
  }
  int cc = tid & 255, rhalf = tid >> 8;
  float bc = b1[cc];
  float s = 0.f, s2 = 0.f;
  int r0 = rhalf*75;
  for (int rr = r0; rr < r0 + 75; ++rr) {
    float acc = 0.f;
#pragma unroll
    for (int i = 0; i < 18; ++i) acc += Tall_s[rr*18 + i] * wl[i*256 + cc];
    outc[(size_t)(jb+rr)*HD + cc] = f2h(acc);
    float vb = acc + bc;
    s += vb; s2 += vb*vb;
  }
  atomicAdd(&stats[cc], s);
  atomicAdd(&stats[HD + cc], s2);
}

// ---------------- fused per-jet Chebyshev layer ----------------
// r15 structure exactly (per-ks WT loads restored); ONLY change: coalesced OUT writes
// via LDS re-staging after the final barrier (OutS aliases the dead Ls/Tn/Tt space).
template<int OMODE>
__global__ __launch_bounds__(1024, 4) void k_cheb(const u16* __restrict__ IN,
                                                  const u16* __restrict__ WTu,
                                                  const int* __restrict__ rowptr,
                                                  const unsigned char* __restrict__ ccol,
                                                  const float* __restrict__ cw,
                                                  const float* __restrict__ statsPrev,
                                                  const float* __restrict__ gP,
                                                  const float* __restrict__ beP,
                                                  const float* __restrict__ bP,
                                                  const float* __restrict__ bCur,
                                                  float* __restrict__ statsCur,
                                                  float* __restrict__ rn,
                                                  u16* __restrict__ OUTp) {
  __shared__ u16 SM[75776];            // Ls | Tn0 | Tn1 | Tt0 | Tt1  (151.5 KB)
  __shared__ float bnA[HD], bnB[HD];   // 2 KB
  u16* const Ls  = SM;                 // 160*192 = 30720
  u16* const Tn0 = SM + 30720;         // 160*64  = 10240
  u16* const Tn1 = SM + 40960;
  u16* const Tt0 = SM + 51200;         // 64*192  = 12288
  u16* const Tt1 = SM + 63488;
  int j = blockIdx.x, tid = threadIdx.x;
  int jb = j*PJ;
  int lane = tid & 63, wid = tid >> 6;
  int wm = wid >> 3, wn = wid & 7;          // 2(M) x 8(N)
  int lr = lane & 15, lg = lane >> 4;
  int ph = wn >> 2, cs = wn & 3;            // prop: half + 16-ch slice
  int cown = cs*16 + lr;
  u16* const Tnp = ph ? Tn1 : Tn0;
  u16* const Ttp = ph ? Tt1 : Tt0;
  // hoisted thread-invariant swizzle offsets (u16 units)
  int key   = lr & 7;
  int segA0 = ((lg    ) ^ key) * 8;
  int segA1 = ((lg + 4) ^ key) * 8;
  int pOff[5] = { segA0, segA1, 64 + segA0, 64 + segA1, 128 + segA0 };
  int ep0 = ((cown >> 3) ^ ((lg & 1)*4 + 0)) * 8 + (cown & 7);
  int ep1 = ((cown >> 3) ^ ((lg & 1)*4 + 1)) * 8 + (cown & 7);
  int ep2 = ((cown >> 3) ^ ((lg & 1)*4 + 2)) * 8 + (cown & 7);
  int ep3 = ((cown >> 3) ^ ((lg & 1)*4 + 3)) * 8 + (cown & 7);
  int cownL = cown * LSTR;
  const f16* WT = (const f16*)WTu;
  const f16* wtb = WT + (size_t)(wn*32 + lr)*1536 + lg*8;

  // BN tables
  if (tid < HD) {
    const float invN = 1.f/(float)NODES;
    float m = statsPrev[tid]*invN;
    float var = statsPrev[HD+tid]*invN - m*m;
    float A = rsqrtf(var + 1e-5f) * gP[tid];
    bnA[tid] = A;
    bnB[tid] = (bP[tid] - m)*A + beP[tid];
  }
  // zero Ls + Tn pad rows (150..159, both halves)
  {
    u16x8 z = {0,0,0,0,0,0,0,0};
    for (int i = tid; i < 3840; i += 1024) *(u16x8*)&Ls[i*8] = z;
    for (int i = tid; i < 160; i += 1024) {
      int h = i >= 80 ? 1 : 0;
      int rem = i - h*80;
      int row = 150 + (rem >> 3), seg = rem & 7;
      u16* TnH = h ? Tn1 : Tn0;
      *(u16x8*)&TnH[row*TNS + seg*8] = z;
    }
  }
  __syncthreads();
  // build dense 2*Lhat in LDS from CSR (thread r owns row r)
  if (tid < PJ) {
    int es = rowptr[jb + tid], ee = rowptr[jb + tid + 1];
    for (int e = es; e < ee; ++e) {
      int c = (int)ccol[e];
      int a = tid*LSTR + swz(c >> 3, tid)*8 + (c & 7);
      Ls[a] = f2h(h2f(Ls[a]) + 2.f*cw[e]);
    }
  }
  f32x4 acc[5][2];
#pragma unroll
  for (int a = 0; a < 5; ++a)
#pragma unroll
    for (int b = 0; b < 2; ++b) acc[a][b] = (f32x4)0.f;

  u16x4 tc0, tc1, tc2, tc3, tc4, tp0, tp1, tp2, tp3, tp4;

  for (int qp = 0; qp < 2; ++qp) {
    __syncthreads();   // prior-pair reads done; Ls build / bn staged at qp=0
    // stage T0 = lrelu(BN(IN)) for quarters (qp*2, qp*2+1); rows < 150 only
    for (int i = tid; i < 2400; i += 1024) {
      int h = (i >= 1200) ? 1 : 0;
      int rem = i - h*1200;
      int row = rem >> 3, seg = rem & 7;
      int c0 = (qp*2+h)*64 + seg*8;
      u16x8 v = *(const u16x8*)&IN[(size_t)(jb+row)*HD + c0];
      u16x8 o;
#pragma unroll
      for (int u = 0; u < 8; ++u) {
        float f = h2f(v[u])*bnA[c0+u] + bnB[c0+u];
        o[u] = f2h((f > 0.f) ? f : 0.01f*f);
      }
      u16* TnH = h ? Tn1 : Tn0;
      *(u16x8*)&TnH[row*TNS + (seg ^ (row & 7))*8] = o;
    }
    __syncthreads();
    // build Ttr (swizzled both sides)
    for (int i = tid; i < 2560; i += 1024) {
      int h = (i >= 1280) ? 1 : 0;
      int rem = i - h*1280;
      int c = rem & 63, m = rem >> 6;
      u16* TnH = h ? Tn1 : Tn0;
      u16* TtH = h ? Tt1 : Tt0;
      u16x8 v;
#pragma unroll
      for (int u = 0; u < 8; ++u) {
        int r = m*8 + u;
        v[u] = TnH[r*TNS + ((c >> 3) ^ (r & 7))*8 + (c & 7)];
      }
      *(u16x8*)&TtH[c*LSTR + swz(m, c)*8] = v;
    }
    // own-slot T0 into named registers
#define TINIT(MF, TC, TP) { int r0 = wm*80 + MF*16 + lg*4; u16x4 t; \
    t[0] = Tnp[(r0+0)*TNS + ep0]; t[1] = Tnp[(r0+1)*TNS + ep1]; \
    t[2] = Tnp[(r0+2)*TNS + ep2]; t[3] = Tnp[(r0+3)*TNS + ep3]; \
    TC = t; TP = t; }
    TINIT(0, tc0, tp0) TINIT(1, tc1, tp1) TINIT(2, tc2, tp2) TINIT(3, tc3, tp3) TINIT(4, tc4, tp4)
#undef TINIT
    __syncthreads();
#pragma unroll 1
    for (int t = 0; t < 6; ++t) {
      // ---- weight GEMM, both halves: acc += T_t @ W_t (wave tile 80x32) ----
#pragma unroll
      for (int h = 0; h < 2; ++h) {
        int kbase = t*256 + (qp*2+h)*64;
        u16* const TnH = h ? Tn1 : Tn0;
#pragma unroll
        for (int ks = 0; ks < 64; ks += 32) {
          int segA = (ks == 0) ? segA0 : segA1;
          f16x8 a[5], bv[2];
#pragma unroll
          for (int nf = 0; nf < 2; ++nf)
            bv[nf] = *(const f16x8*)&wtb[nf*24576 + kbase + ks];
#pragma unroll
          for (int mf = 0; mf < 5; ++mf) {
            int row = wm*80 + mf*16 + lr;
            a[mf] = *(const f16x8*)&TnH[row*TNS + segA];
          }
#pragma unroll
          for (int nf = 0; nf < 2; ++nf)
#pragma unroll
            for (int mf = 0; mf < 5; ++mf)
              acc[mf][nf] = __builtin_amdgcn_mfma_f32_16x16x32_f16(a[mf], bv[nf], acc[mf][nf], 0, 0, 0);
        }
      }
      if (t < 5) {
        // ---- prop MFMA: pacc = L2 @ T_t for this wave's (half, 16-ch slice) ----
        f32x4 pacc[5];
#pragma unroll
        for (int mf = 0; mf < 5; ++mf) pacc[mf] = (f32x4)0.f;
#pragma unroll
        for (int ks = 0; ks < 5; ++ks) {
          f16x8 b = *(const f16x8*)&Ttp[cownL + pOff[ks]];
#pragma unroll
          for (int mf = 0; mf < 5; ++mf) {
            int row = wm*80 + mf*16 + lr;
            f16x8 a = *(const f16x8*)&Ls[row*LSTR + pOff[ks]];
            pacc[mf] = __builtin_amdgcn_mfma_f32_16x16x32_f16(a, b, pacc[mf], 0, 0, 0);
          }
        }
        __syncthreads();
#define TEPI(MF, TC, TP) { int r0 = wm*80 + MF*16 + lg*4; u16x4 o; \
        { float v0_ = (t == 0) ? 0.5f*pacc[MF][0] : pacc[MF][0] - h2f(TP[0]); o[0] = f2h(v0_); } \
        { float v1_ = (t == 0) ? 0.5f*pacc[MF][1] : pacc[MF][1] - h2f(TP[1]); o[1] = f2h(v1_); } \
        { float v2_ = (t == 0) ? 0.5f*pacc[MF][2] : pacc[MF][2] - h2f(TP[2]); o[2] = f2h(v2_); } \
        { float v3_ = (t == 0) ? 0.5f*pacc[MF][3] : pacc[MF][3] - h2f(TP[3]); o[3] = f2h(v3_); } \
        Tnp[(r0+0)*TNS + ep0] = o[0]; Tnp[(r0+1)*TNS + ep1] = o[1]; \
        Tnp[(r0+2)*TNS + ep2] = o[2]; Tnp[(r0+3)*TNS + ep3] = o[3]; \
        int sgT = wm*10 + MF*2 + (lg >> 1); \
        int segT = (sgT & ~7) | ((sgT & 7) ^ key); \
        *(u16x4*)&Ttp[cownL + segT*8 + (lg & 1)*4] = o; \
        TP = TC; TC = o; }
        TEPI(0, tc0, tp0) TEPI(1, tc1, tp1) TEPI(2, tc2, tp2) TEPI(3, tc3, tp3) TEPI(4, tc4, tp4)
#undef TEPI
        __syncthreads();
      }
    }
  }
  // ---- epilogue: stats/rowsumsq from regs, OUT staged to LDS then coalesced ----
  __syncthreads();   // all waves done reading SM
  u16* const OutS = SM;   // [150][OSTR] u16 = 79.2 KB, aliases Ls/Tn/Tt
  if (OMODE == 0) {
#pragma unroll
    for (int nf = 0; nf < 2; ++nf) {
      int col = wn*32 + nf*16 + lr;
      float bc = bCur[col];
      float s = 0.f, s2 = 0.f;
#pragma unroll
      for (int mf = 0; mf < 5; ++mf) {
        int row = wm*80 + mf*16 + lg*4;
#pragma unroll
        for (int e = 0; e < 4; ++e) {
          int r = row + e;
          if (r < PJ) {
            float v = acc[mf][nf][e];
            OutS[r*OSTR + col] = f2h(v);
            float vb = v + bc;
            s += vb; s2 += vb*vb;
          }
        }
      }
      s  += __shfl_xor(s, 16, 64);  s  += __shfl_xor(s, 32, 64);
      s2 += __shfl_xor(s2, 16, 64); s2 += __shfl_xor(s2, 32, 64);
      if (lg == 0) {
        atomicAdd(&statsCur[col], s);
        atomicAdd(&statsCur[HD + col], s2);
      }
    }
  } else {
    float bc[2];
#pragma unroll
    for (int nf = 0; nf < 2; ++nf) bc[nf] = bCur[wn*32 + nf*16 + lr];
#pragma unroll
    for (int mf = 0; mf < 5; ++mf) {
      int row = wm*80 + mf*16 + lg*4;
#pragma unroll
      for (int e = 0; e < 4; ++e) {
        int r = row + e;
        float srow = 0.f;
        if (r < PJ) {
#pragma unroll
          for (int nf = 0; nf < 2; ++nf) {
            int col = wn*32 + nf*16 + lr;
            float v = acc[mf][nf][e];
            OutS[r*OSTR + col] = f2h(v);
            float vb = v + bc[nf];
            srow += vb*vb;
          }
        }
        srow += __shfl_xor(srow, 1, 64);
        srow += __shfl_xor(srow, 2, 64);
        srow += __shfl_xor(srow, 4, 64);
        srow += __shfl_xor(srow, 8, 64);
        if (lr == 0 && r < PJ) atomicAdd(&rn[jb + r], srow);
      }
    }
  }
  __syncthreads();
  // coalesced write: 150 rows x 512B
  for (int i = tid; i < 4800; i += 1024) {
    int row = i >> 5, seg = i & 31;
    *(u16x8*)&OUTp[(size_t)(jb+row)*HD + seg*8] = *(const u16x8*)&OutS[row*OSTR + seg*8];
  }
}

// ---------------- distance softmax pooling, fused row-normalize ----------------

__global__ __launch_bounds__(256) void k_pool(const u16* __restrict__ h, const float* __restrict__ rn,
                                              const float* __restrict__ bias, const float* __restrict__ x,
                                              const float* __restrict__ centers, const float* __restrict__ log_temp,
                                              float* __restrict__ out) {
  __shared__ float a_s[PJ][NCL];
  __shared__ float colsum[NCL];
  __shared__ float inv_s[PJ];
  int j = blockIdx.x;
  int tid = threadIdx.x;
  float T = expf(fminf(fmaxf(log_temp[0], -2.f), 3.f));
  if (tid < PJ) {
    int g = j*PJ + tid;
    inv_s[tid] = 1.f / fmaxf(sqrtf(rn[g]), 1e-12f);
    float eta = x[(size_t)g*3], phi = x[(size_t)g*3 + 1];
    float d[NCL];
    float dmin = 1e30f;
#pragma unroll
    for (int k = 0; k < NCL; ++k) {
      float dx = eta - centers[2*k], dy = phi - centers[2*k+1];
      d[k] = dx*dx + dy*dy;
      dmin = fminf(dmin, d[k]);
    }
    float s = 0.f, ek[NCL];
#pragma unroll
    for (int k = 0; k < NCL; ++k) { ek[k] = expf(-T*(d[k]-dmin)); s += ek[k]; }
    float invs = 1.f/s;
#pragma unroll
    for (int k = 0; k < NCL; ++k) a_s[tid][k] = ek[k]*invs;
  }
  __syncthreads();
  if (tid < NCL) {
    float s = 0.f;
    for (int n = 0; n < PJ; ++n) s += a_s[n][tid];
    colsum[tid] = s;
  }
  __syncthreads();
  int c = tid;
  float bc = bias[c];
  float acc[NCL] = {};
  for (int n = 0; n < PJ; ++n) {
    float hv = (h2f(h[(size_t)(j*PJ + n)*HD + c]) + bc) * inv_s[n];
#pragma unroll
    for (int k = 0; k < NCL; ++k) acc[k] += a_s[n][k]*hv;
  }
#pragma unroll
  for (int k = 0; k < NCL; ++k)
    out[(size_t)j*(NCL*HD) + k*HD + c] = acc[k] / (colsum[k] + 1e-8f);
}

// ---------------- host ----------------

extern "C" void kernel_launch(void* const* d_in, const int* in_sizes, int n_in,
                              void* d_out, int out_size, void* d_ws, size_t ws_size,
                              hipStream_t stream) {
  (void)in_sizes; (void)n_in; (void)out_size;
  const float* x   = (const float*)d_in[0];
  const int*   ei  = (const int*)d_in[1];
  const int*   srcA = ei;
  const int*   tgtA = ei + NEDGE;
  const float* W1  = (const float*)d_in[3];
  const float* b1  = (const float*)d_in[4];
  const float* W2  = (const float*)d_in[5];
  const float* b2  = (const float*)d_in[6];
  const float* W3  = (const float*)d_in[7];
  const float* b3  = (const float*)d_in[8];
  const float* W4  = (const float*)d_in[9];
  const float* b4  = (const float*)d_in[10];
  const float* g1  = (const float*)d_in[11];
  const float* be1 = (const float*)d_in[12];
  const float* g2  = (const float*)d_in[13];
  const float* be2 = (const float*)d_in[14];
  const float* g3  = (const float*)d_in[15];
  const float* be3 = (const float*)d_in[16];
  const float* centers  = (const float*)d_in[17];
  const float* log_temp = (const float*)d_in[18];
  float* out = (float*)d_out;

  auto rb = [](size_t b) { return (b + 255) & ~(size_t)255; };
  size_t need = 2*rb((size_t)NODES*HD*2)            // OUTA, OUTB
              + rb((size_t)3*256*1536*2)            // Wcat
              + 3*rb((size_t)NODES*4)               // dis, counts, cursor
              + rb((size_t)(NODES+1)*4)             // rowptr
              + rb((size_t)NEDGE)                   // ccol
              + rb((size_t)NEDGE*4)                 // cw
              + rb((size_t)3*2*HD*4)                // stats x3
              + rb((size_t)NODES*4);                // rn
  fprintf(stderr, "[kernel_launch] ws_size=%zu need=%zu\n", ws_size, need);
  if (d_ws == nullptr || ws_size < need) {
    float code = 1.0e6f + (float)(ws_size >> 20);
    k_diag<<<1, 1, 0, stream>>>(out, code);
    return;
  }

  char* wp = (char*)d_ws;
  auto alloc = [&](size_t b) -> void* {
    void* p = (void*)wp;
    wp += (b + 255) & ~(size_t)255;
    return p;
  };
  u16*   OUTA = (u16*)alloc((size_t)NODES*HD*2);
  u16*   OUTB = (u16*)alloc((size_t)NODES*HD*2);
  u16*   Wcat = (u16*)alloc((size_t)3*256*1536*2);
  float* dis  = (float*)alloc((size_t)NODES*4);
  int*   counts = (int*)alloc((size_t)NODES*4);
  int*   cursor = (int*)alloc((size_t)NODES*4);
  int*   rowptr = (int*)alloc((size_t)(NODES+1)*4);
  unsigned char* ccol = (unsigned char*)alloc((size_t)NEDGE);
  float* cw     = (float*)alloc((size_t)NEDGE*4);
  float* stats  = (float*)alloc((size_t)3*2*HD*4);   // [3][512]
  float* rn     = (float*)alloc((size_t)NODES*4);
  float* s0 = stats, *s1 = stats + 512, *s2 = stats + 1024;

  // graph preprocessing
  hipMemsetAsync(counts, 0, (size_t)NODES*4, stream);
  k_discounts<<<(NEDGE+255)/256, 256, 0, stream>>>(tgtA, counts, dis);
  k_scan<<<(NJETS+255)/256, 256, 0, stream>>>(counts, rowptr, cursor);
  k_fill<<<(NEDGE+255)/256, 256, 0, stream>>>(srcA, tgtA, dis, cursor, ccol, cw);

  // W conversion + all stats/rn zeroing (independent of layer 1)
  k_prepW<<<(3*256*1536+255)/256, 256, 0, stream>>>(W2, W3, W4, Wcat, stats, rn);

  // ---- layer 1 fused (props + GEMM + stats) ----
  k_l1<<<NJETS, 512, 0, stream>>>(x, rowptr, ccol, cw, W1, b1, s0, OUTA);

  // ---- layers 2..4: fused all-MFMA Cheb, BN-on-stage, in-block L build ----
  k_cheb<0><<<NJETS, 1024, 0, stream>>>(OUTA, Wcat,            rowptr, ccol, cw, s0, g1, be1, b1, b2, s1, rn, OUTB);
  k_cheb<0><<<NJETS, 1024, 0, stream>>>(OUTB, Wcat + 393216,   rowptr, ccol, cw, s1, g2, be2, b2, b3, s2, rn, OUTA);
  k_cheb<1><<<NJETS, 1024, 0, stream>>>(OUTA, Wcat + 2*393216, rowptr, ccol, cw, s2, g3, be3, b3, b4, s2, rn, OUTB);

  // ---- pooling (fused rownorm) ----
  k_pool<<<NJETS, 256, 0, stream>>>(OUTB, rn, b4, x, centers, log_temp, out);
}

// Round 18
// 1253.352 us; speedup vs baseline: 1.3308x; 1.1000x over previous
//
#include <hip/hip_runtime.h>
#include <cstdio>

#define NODES 153600
#define PJ 150
#define NJETS 1024
#define DEG 16
#define NEDGE (NODES*DEG)
#define HD 256
#define NCL 10

#define LSTR 192   // Ls/Tt row stride (u16): conflicts killed by seg XOR-swizzle (key = lr&7)
#define TNS  64    // Tn row stride (u16): seg XOR-swizzle (key = lr&7)

typedef unsigned short u16;  // fp16 bit pattern
typedef _Float16 f16;
typedef f16 f16x8 __attribute__((ext_vector_type(8)));
typedef u16 u16x8 __attribute__((ext_vector_type(8)));
typedef u16 u16x4 __attribute__((ext_vector_type(4)));
typedef float f32x4 __attribute__((ext_vector_type(4)));

__device__ inline float h2f(u16 u) { union { u16 s; f16 h; } v; v.s = u; return (float)v.h; }
__device__ inline u16 f2h(float f) { union { u16 s; f16 h; } v; v.h = (f16)f; return v.s; }
// XOR-swizzle a 16B segment index within its aligned 8-seg (128B) block
__device__ inline int swz(int seg, int key) { return (seg & ~7) | ((seg & 7) ^ (key & 7)); }

// ---------------- diagnostic ----------------
__global__ void k_diag(float* out, float code) {
  if (blockIdx.x == 0 && threadIdx.x == 0) out[0] = code;
}

// ---------------- graph preprocessing ----------------

__global__ __launch_bounds__(256) void k_discounts(const int* __restrict__ tgt,
                                                   int* __restrict__ counts,
                                                   float* __restrict__ dis) {
  int i = blockIdx.x*256 + threadIdx.x;
  if (i < NEDGE) atomicAdd(&counts[tgt[i]], 1);
  if (i < NODES) {
    int cnt = 0;
#pragma unroll
    for (int j = 0; j < DEG; ++j) cnt += (tgt[i*DEG + j] != i) ? 1 : 0;
    dis[i] = (cnt > 0) ? rsqrtf((float)cnt) : 0.f;
  }
}

__global__ __launch_bounds__(256) void k_scan(const int* __restrict__ counts, int* __restrict__ rowptr, int* __restrict__ cursor) {
  int j = blockIdx.x*256 + threadIdx.x;
  if (j >= NJETS) return;
  int run = j*PJ*DEG;
  for (int l = 0; l < PJ; ++l) {
    int idx = j*PJ + l;
    int cnt = counts[idx];
    rowptr[idx] = run;
    cursor[idx] = run;
    run += cnt;
  }
  if (j == 0) rowptr[NODES] = NEDGE;
}

__global__ __launch_bounds__(256) void k_fill(const int* __restrict__ src_, const int* __restrict__ tgt_,
                                              const float* __restrict__ dis, int* __restrict__ cursor,
                                              unsigned char* __restrict__ ccol, float* __restrict__ cw) {
  int e = blockIdx.x*256 + threadIdx.x;
  if (e >= NEDGE) return;
  int s = src_[e], t = tgt_[e];
  int pos = atomicAdd(&cursor[t], 1);
  ccol[pos] = (unsigned char)(s % PJ);
  cw[pos] = (s != t) ? -(dis[s]*dis[t]) : 0.f;
}

// ---------------- W conversion + stats/rn zeroing ----------------
__global__ __launch_bounds__(256) void k_prepW(const float* __restrict__ Wa, const float* __restrict__ Wb,
                                               const float* __restrict__ Wc, u16* __restrict__ WT,
                                               float* __restrict__ stats /*[3][512]*/,
                                               float* __restrict__ rn) {
  int i = blockIdx.x*256 + threadIdx.x;
  if (i < 3*256*1536) {
    int layer = i / (256*1536);
    int rem = i - layer*(256*1536);
    int cout = rem / 1536, k = rem - cout*1536;
    int term = k >> 8, cin = k & 255;
    const float* W = (layer == 0) ? Wa : (layer == 1) ? Wb : Wc;
    WT[i] = f2h(W[(size_t)term*65536 + cin*256 + cout]);
  }
  if (i < 3*2*HD) stats[i] = 0.f;
  if (i < NODES) rn[i] = 0.f;
}

// ---------------- layer 1 fused: 5 sparse props (din=3) + [150x18]@[18x256] + BN stats ------------
__global__ __launch_bounds__(512) void k_l1(const float* __restrict__ x,
                                            const int* __restrict__ rowptr,
                                            const unsigned char* __restrict__ ccol,
                                            const float* __restrict__ cw,
                                            const float* __restrict__ W1,
                                            const float* __restrict__ b1,
                                            float* __restrict__ stats,
                                            u16* __restrict__ outc) {
  __shared__ float Ta[450], Tb[450];
  __shared__ float Tall_s[PJ*18];
  __shared__ float wl[18*256];
  __shared__ float cw_s[PJ*DEG];
  __shared__ u16  col_s[PJ*DEG];
  __shared__ int  rp_s[PJ+1];
  int j = blockIdx.x, tid = threadIdx.x;
  int jb = j*PJ, e0 = jb*DEG;
  for (int i = tid; i < 18*256; i += 512) wl[i] = W1[i];
  for (int i = tid; i < PJ*DEG; i += 512) { cw_s[i] = cw[e0+i]; col_s[i] = (u16)ccol[e0+i]; }
  for (int i = tid; i < PJ+1; i += 512) rp_s[i] = rowptr[jb+i] - e0;
  if (tid < 450) Ta[tid] = x[(size_t)jb*3 + tid];
  __syncthreads();
  int r = tid/3, c = tid - r*3;
  float* cur = Ta; float* oth = Tb;
  if (tid < 450) Tall_s[r*18 + c] = cur[tid];
  for (int t = 1; t < 6; ++t) {
    if (tid < 450) {
      int es = rp_s[r], ee = rp_s[r+1];
      float acc = 0.f;
      for (int e = es; e < ee; ++e) acc += cw_s[e]*cur[(int)col_s[e]*3 + c];
      float v = (t == 1) ? acc : 2.f*acc - oth[tid];
      oth[tid] = v;
      Tall_s[r*18 + t*3 + c] = v;
    }
    __syncthreads();
    float* tmp = cur; cur = oth; oth = tmp;
  }
  int cc = tid & 255, rhalf = tid >> 8;
  float bc = b1[cc];
  float s = 0.f, s2 = 0.f;
  int r0 = rhalf*75;
  for (int rr = r0; rr < r0 + 75; ++rr) {
    float acc = 0.f;
#pragma unroll
    for (int i = 0; i < 18; ++i) acc += Tall_s[rr*18 + i] * wl[i*256 + cc];
    outc[(size_t)(jb+rr)*HD + cc] = f2h(acc);
    float vb = acc + bc;
    s += vb; s2 += vb*vb;
  }
  atomicAdd(&stats[cc], s);
  atomicAdd(&stats[HD + cc], s2);
}

// ---------------- fused per-jet Chebyshev layer ----------------
// EXACT r15 structure (proven 1273 us) + s_setprio(1) around MFMA clusters (T5).
template<int OMODE>
__global__ __launch_bounds__(1024, 4) void k_cheb(const u16* __restrict__ IN,
                                                  const u16* __restrict__ WTu,
                                                  const int* __restrict__ rowptr,
                                                  const unsigned char* __restrict__ ccol,
                                                  const float* __restrict__ cw,
                                                  const float* __restrict__ statsPrev,
                                                  const float* __restrict__ gP,
                                                  const float* __restrict__ beP,
                                                  const float* __restrict__ bP,
                                                  const float* __restrict__ bCur,
                                                  float* __restrict__ statsCur,
                                                  float* __restrict__ rn,
                                                  u16* __restrict__ OUTp) {
  __shared__ u16 Ls[160*LSTR];         // 61.4 KB
  __shared__ u16 Tn[2][160*TNS];       // 41.0 KB
  __shared__ u16 Tt[2][64*LSTR];       // 49.2 KB
  __shared__ float bnA[HD], bnB[HD];   // 2 KB   -> 153.6 KB total
  int j = blockIdx.x, tid = threadIdx.x;
  int jb = j*PJ;
  int lane = tid & 63, wid = tid >> 6;
  int wm = wid >> 3, wn = wid & 7;          // 2(M) x 8(N)
  int lr = lane & 15, lg = lane >> 4;
  int ph = wn >> 2, cs = wn & 3;            // prop: half + 16-ch slice
  int cown = cs*16 + lr;
  // hoisted thread-invariant swizzle offsets (u16 units)
  int key   = lr & 7;
  int segA0 = ((lg    ) ^ key) * 8;
  int segA1 = ((lg + 4) ^ key) * 8;
  int pOff[5] = { segA0, segA1, 64 + segA0, 64 + segA1, 128 + segA0 };
  int ep0 = ((cown >> 3) ^ ((lg & 1)*4 + 0)) * 8 + (cown & 7);
  int ep1 = ((cown >> 3) ^ ((lg & 1)*4 + 1)) * 8 + (cown & 7);
  int ep2 = ((cown >> 3) ^ ((lg & 1)*4 + 2)) * 8 + (cown & 7);
  int ep3 = ((cown >> 3) ^ ((lg & 1)*4 + 3)) * 8 + (cown & 7);
  int cownL = cown * LSTR;
  const f16* WT = (const f16*)WTu;
  const f16* wtb = WT + (size_t)(wn*32 + lr)*1536 + lg*8;

  // BN tables
  if (tid < HD) {
    const float invN = 1.f/(float)NODES;
    float m = statsPrev[tid]*invN;
    float var = statsPrev[HD+tid]*invN - m*m;
    float A = rsqrtf(var + 1e-5f) * gP[tid];
    bnA[tid] = A;
    bnB[tid] = (bP[tid] - m)*A + beP[tid];
  }
  // zero Ls + Tn pad rows (150..159, both halves)
  {
    u16x8 z = {0,0,0,0,0,0,0,0};
    for (int i = tid; i < 3840; i += 1024) *(u16x8*)&Ls[i*8] = z;
    for (int i = tid; i < 160; i += 1024) {
      int h = i >= 80 ? 1 : 0;
      int rem = i - h*80;
      int row = 150 + (rem >> 3), seg = rem & 7;
      *(u16x8*)&Tn[h][row*TNS + seg*8] = z;
    }
  }
  __syncthreads();
  // build dense 2*Lhat in LDS from CSR (thread r owns row r)
  if (tid < PJ) {
    int es = rowptr[jb + tid], ee = rowptr[jb + tid + 1];
    for (int e = es; e < ee; ++e) {
      int c = (int)ccol[e];
      int a = tid*LSTR + swz(c >> 3, tid)*8 + (c & 7);
      Ls[a] = f2h(h2f(Ls[a]) + 2.f*cw[e]);
    }
  }
  f32x4 acc[5][2];
#pragma unroll
  for (int a = 0; a < 5; ++a)
#pragma unroll
    for (int b = 0; b < 2; ++b) acc[a][b] = (f32x4)0.f;

  u16x4 tc0, tc1, tc2, tc3, tc4, tp0, tp1, tp2, tp3, tp4;

  for (int qp = 0; qp < 2; ++qp) {
    __syncthreads();   // prior-pair reads done; Ls build / bn staged at qp=0
    // stage T0 = lrelu(BN(IN)) for quarters (qp*2, qp*2+1); rows < 150 only
    for (int i = tid; i < 2400; i += 1024) {
      int h = (i >= 1200) ? 1 : 0;
      int rem = i - h*1200;
      int row = rem >> 3, seg = rem & 7;
      int c0 = (qp*2+h)*64 + seg*8;
      u16x8 v = *(const u16x8*)&IN[(size_t)(jb+row)*HD + c0];
      u16x8 o;
#pragma unroll
      for (int u = 0; u < 8; ++u) {
        float f = h2f(v[u])*bnA[c0+u] + bnB[c0+u];
        o[u] = f2h((f > 0.f) ? f : 0.01f*f);
      }
      *(u16x8*)&Tn[h][row*TNS + (seg ^ (row & 7))*8] = o;
    }
    __syncthreads();
    // build Ttr (swizzled both sides)
    for (int i = tid; i < 2560; i += 1024) {
      int h = (i >= 1280) ? 1 : 0;
      int rem = i - h*1280;
      int c = rem & 63, m = rem >> 6;
      u16x8 v;
#pragma unroll
      for (int u = 0; u < 8; ++u) {
        int r = m*8 + u;
        v[u] = Tn[h][r*TNS + ((c >> 3) ^ (r & 7))*8 + (c & 7)];
      }
      *(u16x8*)&Tt[h][c*LSTR + swz(m, c)*8] = v;
    }
    // own-slot T0 into named registers
#define TINIT(MF, TC, TP) { int r0 = wm*80 + MF*16 + lg*4; u16x4 t; \
    t[0] = Tn[ph][(r0+0)*TNS + ep0]; t[1] = Tn[ph][(r0+1)*TNS + ep1]; \
    t[2] = Tn[ph][(r0+2)*TNS + ep2]; t[3] = Tn[ph][(r0+3)*TNS + ep3]; \
    TC = t; TP = t; }
    TINIT(0, tc0, tp0) TINIT(1, tc1, tp1) TINIT(2, tc2, tp2) TINIT(3, tc3, tp3) TINIT(4, tc4, tp4)
#undef TINIT
    __syncthreads();
#pragma unroll 1
    for (int t = 0; t < 6; ++t) {
      // ---- weight GEMM, both halves: acc += T_t @ W_t (wave tile 80x32) ----
#pragma unroll
      for (int h = 0; h < 2; ++h) {
        int kbase = t*256 + (qp*2+h)*64;
#pragma unroll
        for (int ks = 0; ks < 64; ks += 32) {
          int segA = (ks == 0) ? segA0 : segA1;
          f16x8 a[5], bv[2];
#pragma unroll
          for (int nf = 0; nf < 2; ++nf)
            bv[nf] = *(const f16x8*)&wtb[nf*24576 + kbase + ks];
#pragma unroll
          for (int mf = 0; mf < 5; ++mf) {
            int row = wm*80 + mf*16 + lr;
            a[mf] = *(const f16x8*)&Tn[h][row*TNS + segA];
          }
          __builtin_amdgcn_s_setprio(1);
#pragma unroll
          for (int nf = 0; nf < 2; ++nf)
#pragma unroll
            for (int mf = 0; mf < 5; ++mf)
              acc[mf][nf] = __builtin_amdgcn_mfma_f32_16x16x32_f16(a[mf], bv[nf], acc[mf][nf], 0, 0, 0);
          __builtin_amdgcn_s_setprio(0);
        }
      }
      if (t < 5) {
        // ---- prop MFMA: pacc = L2 @ T_t for this wave's (half, 16-ch slice) ----
        f32x4 pacc[5];
#pragma unroll
        for (int mf = 0; mf < 5; ++mf) pacc[mf] = (f32x4)0.f;
#pragma unroll
        for (int ks = 0; ks < 5; ++ks) {
          f16x8 b = *(const f16x8*)&Tt[ph][cownL + pOff[ks]];
          __builtin_amdgcn_s_setprio(1);
#pragma unroll
          for (int mf = 0; mf < 5; ++mf) {
            int row = wm*80 + mf*16 + lr;
            f16x8 a = *(const f16x8*)&Ls[row*LSTR + pOff[ks]];
            pacc[mf] = __builtin_amdgcn_mfma_f32_16x16x32_f16(a, b, pacc[mf], 0, 0, 0);
          }
          __builtin_amdgcn_s_setprio(0);
        }
        __syncthreads();
#define TEPI(MF, TC, TP) { int r0 = wm*80 + MF*16 + lg*4; u16x4 o; \
        { float v0_ = (t == 0) ? 0.5f*pacc[MF][0] : pacc[MF][0] - h2f(TP[0]); o[0] = f2h(v0_); } \
        { float v1_ = (t == 0) ? 0.5f*pacc[MF][1] : pacc[MF][1] - h2f(TP[1]); o[1] = f2h(v1_); } \
        { float v2_ = (t == 0) ? 0.5f*pacc[MF][2] : pacc[MF][2] - h2f(TP[2]); o[2] = f2h(v2_); } \
        { float v3_ = (t == 0) ? 0.5f*pacc[MF][3] : pacc[MF][3] - h2f(TP[3]); o[3] = f2h(v3_); } \
        Tn[ph][(r0+0)*TNS + ep0] = o[0]; Tn[ph][(r0+1)*TNS + ep1] = o[1]; \
        Tn[ph][(r0+2)*TNS + ep2] = o[2]; Tn[ph][(r0+3)*TNS + ep3] = o[3]; \
        int sgT = wm*10 + MF*2 + (lg >> 1); \
        int segT = (sgT & ~7) | ((sgT & 7) ^ key); \
        *(u16x4*)&Tt[ph][cownL + segT*8 + (lg & 1)*4] = o; \
        TP = TC; TC = o; }
        TEPI(0, tc0, tp0) TEPI(1, tc1, tp1) TEPI(2, tc2, tp2) TEPI(3, tc3, tp3) TEPI(4, tc4, tp4)
#undef TEPI
        __syncthreads();
      }
    }
  }
  // ---- OUT epilogue + fused stats / rowsumsq (r15 scattered-write form) ----
  if (OMODE == 0) {
#pragma unroll
    for (int nf = 0; nf < 2; ++nf) {
      int col = wn*32 + nf*16 + lr;
      float bc = bCur[col];
      float s = 0.f, s2 = 0.f;
#pragma unroll
      for (int mf = 0; mf < 5; ++mf) {
        int row = wm*80 + mf*16 + lg*4;
#pragma unroll
        for (int e = 0; e < 4; ++e) {
          int r = row + e;
          if (r < PJ) {
            float v = acc[mf][nf][e];
            OUTp[(size_t)(jb+r)*HD + col] = f2h(v);
            float vb = v + bc;
            s += vb; s2 += vb*vb;
          }
        }
      }
      s  += __shfl_xor(s, 16, 64);  s  += __shfl_xor(s, 32, 64);
      s2 += __shfl_xor(s2, 16, 64); s2 += __shfl_xor(s2, 32, 64);
      if (lg == 0) {
        atomicAdd(&statsCur[col], s);
        atomicAdd(&statsCur[HD + col], s2);
      }
    }
  } else {
    float bc[2];
#pragma unroll
    for (int nf = 0; nf < 2; ++nf) bc[nf] = bCur[wn*32 + nf*16 + lr];
#pragma unroll
    for (int mf = 0; mf < 5; ++mf) {
      int row = wm*80 + mf*16 + lg*4;
#pragma unroll
      for (int e = 0; e < 4; ++e) {
        int r = row + e;
        float srow = 0.f;
        if (r < PJ) {
#pragma unroll
          for (int nf = 0; nf < 2; ++nf) {
            int col = wn*32 + nf*16 + lr;
            float v = acc[mf][nf][e];
            OUTp[(size_t)(jb+r)*HD + col] = f2h(v);
            float vb = v + bc[nf];
            srow += vb*vb;
          }
        }
        srow += __shfl_xor(srow, 1, 64);
        srow += __shfl_xor(srow, 2, 64);
        srow += __shfl_xor(srow, 4, 64);
        srow += __shfl_xor(srow, 8, 64);
        if (lr == 0 && r < PJ) atomicAdd(&rn[jb + r], srow);
      }
    }
  }
}

// ---------------- distance softmax pooling, fused row-normalize ----------------

__global__ __launch_bounds__(256) void k_pool(const u16* __restrict__ h, const float* __restrict__ rn,
                                              const float* __restrict__ bias, const float* __restrict__ x,
                                              const float* __restrict__ centers, const float* __restrict__ log_temp,
                                              float* __restrict__ out) {
  __shared__ float a_s[PJ][NCL];
  __shared__ float colsum[NCL];
  __shared__ float inv_s[PJ];
  int j = blockIdx.x;
  int tid = threadIdx.x;
  float T = expf(fminf(fmaxf(log_temp[0], -2.f), 3.f));
  if (tid < PJ) {
    int g = j*PJ + tid;
    inv_s[tid] = 1.f / fmaxf(sqrtf(rn[g]), 1e-12f);
    float eta = x[(size_t)g*3], phi = x[(size_t)g*3 + 1];
    float d[NCL];
    float dmin = 1e30f;
#pragma unroll
    for (int k = 0; k < NCL; ++k) {
      float dx = eta - centers[2*k], dy = phi - centers[2*k+1];
      d[k] = dx*dx + dy*dy;
      dmin = fminf(dmin, d[k]);
    }
    float s = 0.f, ek[NCL];
#pragma unroll
    for (int k = 0; k < NCL; ++k) { ek[k] = expf(-T*(d[k]-dmin)); s += ek[k]; }
    float invs = 1.f/s;
#pragma unroll
    for (int k = 0; k < NCL; ++k) a_s[tid][k] = ek[k]*invs;
  }
  __syncthreads();
  if (tid < NCL) {
    float s = 0.f;
    for (int n = 0; n < PJ; ++n) s += a_s[n][tid];
    colsum[tid] = s;
  }
  __syncthreads();
  int c = tid;
  float bc = bias[c];
  float acc[NCL] = {};
  for (int n = 0; n < PJ; ++n) {
    float hv = (h2f(h[(size_t)(j*PJ + n)*HD + c]) + bc) * inv_s[n];
#pragma unroll
    for (int k = 0; k < NCL; ++k) acc[k] += a_s[n][k]*hv;
  }
#pragma unroll
  for (int k = 0; k < NCL; ++k)
    out[(size_t)j*(NCL*HD) + k*HD + c] = acc[k] / (colsum[k] + 1e-8f);
}

// ---------------- host ----------------

extern "C" void kernel_launch(void* const* d_in, const int* in_sizes, int n_in,
                              void* d_out, int out_size, void* d_ws, size_t ws_size,
                              hipStream_t stream) {
  (void)in_sizes; (void)n_in; (void)out_size;
  const float* x   = (const float*)d_in[0];
  const int*   ei  = (const int*)d_in[1];
  const int*   srcA = ei;
  const int*   tgtA = ei + NEDGE;
  const float* W1  = (const float*)d_in[3];
  const float* b1  = (const float*)d_in[4];
  const float* W2  = (const float*)d_in[5];
  const float* b2  = (const float*)d_in[6];
  const float* W3  = (const float*)d_in[7];
  const float* b3  = (const float*)d_in[8];
  const float* W4  = (const float*)d_in[9];
  const float* b4  = (const float*)d_in[10];
  const float* g1  = (const float*)d_in[11];
  const float* be1 = (const float*)d_in[12];
  const float* g2  = (const float*)d_in[13];
  const float* be2 = (const float*)d_in[14];
  const float* g3  = (const float*)d_in[15];
  const float* be3 = (const float*)d_in[16];
  const float* centers  = (const float*)d_in[17];
  const float* log_temp = (const float*)d_in[18];
  float* out = (float*)d_out;

  auto rb = [](size_t b) { return (b + 255) & ~(size_t)255; };
  size_t need = 2*rb((size_t)NODES*HD*2)            // OUTA, OUTB
              + rb((size_t)3*256*1536*2)            // Wcat
              + 3*rb((size_t)NODES*4)               // dis, counts, cursor
              + rb((size_t)(NODES+1)*4)             // rowptr
              + rb((size_t)NEDGE)                   // ccol
              + rb((size_t)NEDGE*4)                 // cw
              + rb((size_t)3*2*HD*4)                // stats x3
              + rb((size_t)NODES*4);                // rn
  fprintf(stderr, "[kernel_launch] ws_size=%zu need=%zu\n", ws_size, need);
  if (d_ws == nullptr || ws_size < need) {
    float code = 1.0e6f + (float)(ws_size >> 20);
    k_diag<<<1, 1, 0, stream>>>(out, code);
    return;
  }

  char* wp = (char*)d_ws;
  auto alloc = [&](size_t b) -> void* {
    void* p = (void*)wp;
    wp += (b + 255) & ~(size_t)255;
    return p;
  };
  u16*   OUTA = (u16*)alloc((size_t)NODES*HD*2);
  u16*   OUTB = (u16*)alloc((size_t)NODES*HD*2);
  u16*   Wcat = (u16*)alloc((size_t)3*256*1536*2);
  float* dis  = (float*)alloc((size_t)NODES*4);
  int*   counts = (int*)alloc((size_t)NODES*4);
  int*   cursor = (int*)alloc((size_t)NODES*4);
  int*   rowptr = (int*)alloc((size_t)(NODES+1)*4);
  unsigned char* ccol = (unsigned char*)alloc((size_t)NEDGE);
  float* cw     = (float*)alloc((size_t)NEDGE*4);
  float* stats  = (float*)alloc((size_t)3*2*HD*4);   // [3][512]
  float* rn     = (float*)alloc((size_t)NODES*4);
  float* s0 = stats, *s1 = stats + 512, *s2 = stats + 1024;

  // graph preprocessing
  hipMemsetAsync(counts, 0, (size_t)NODES*4, stream);
  k_discounts<<<(NEDGE+255)/256, 256, 0, stream>>>(tgtA, counts, dis);
  k_scan<<<(NJETS+255)/256, 256, 0, stream>>>(counts, rowptr, cursor);
  k_fill<<<(NEDGE+255)/256, 256, 0, stream>>>(srcA, tgtA, dis, cursor, ccol, cw);

  // W conversion + all stats/rn zeroing (independent of layer 1)
  k_prepW<<<(3*256*1536+255)/256, 256, 0, stream>>>(W2, W3, W4, Wcat, stats, rn);

  // ---- layer 1 fused (props + GEMM + stats) ----
  k_l1<<<NJETS, 512, 0, stream>>>(x, rowptr, ccol, cw, W1, b1, s0, OUTA);

  // ---- layers 2..4: fused all-MFMA Cheb, BN-on-stage, in-block L build ----
  k_cheb<0><<<NJETS, 1024, 0, stream>>>(OUTA, Wcat,            rowptr, ccol, cw, s0, g1, be1, b1, b2, s1, rn, OUTB);
  k_cheb<0><<<NJETS, 1024, 0, stream>>>(OUTB, Wcat + 393216,   rowptr, ccol, cw, s1, g2, be2, b2, b3, s2, rn, OUTA);
  k_cheb<1><<<NJETS, 1024, 0, stream>>>(OUTA, Wcat + 2*393216, rowptr, ccol, cw, s2, g3, be3, b3, b4, s2, rn, OUTB);

  // ---- pooling (fused rownorm) ----
  k_pool<<<NJETS, 256, 0, stream>>>(OUTB, rn, b4, x, centers, log_temp, out);
}